// Round 5
// baseline (441.189 us; speedup 1.0000x reference)
//
#include <hip/hip_runtime.h>
#include <hip/hip_bf16.h>
#include <cstdint>
#include <cstddef>

typedef __bf16 bf16_t;
typedef __bf16 bf16x8 __attribute__((ext_vector_type(8)));
typedef float f32x4 __attribute__((ext_vector_type(4)));

static __device__ __forceinline__ void st_out(float* p, float v) { *p = v; }
static __device__ __forceinline__ void st_out(bf16_t* p, float v) { *p = (bf16_t)v; }

static __device__ __forceinline__ void async_cp16(const bf16_t* g, bf16_t* l) {
  __builtin_amdgcn_global_load_lds(
      (const __attribute__((address_space(1))) void*)g,
      (__attribute__((address_space(3))) void*)l, 16, 0, 0);
}

// =====================================================================
// prep: all setup work in ONE launch. 1D grid, block ranges:
// [0,2048)      cvt hs f32->bf16
// [2048,6144)   4x 1024x1024 weight transposes (+ bf16 straight copies Wq,Wk)
// [6144,6400)   ta transpose [2][1024][64] -> [2][64][1024]   (q,k)
// [6400,6656)   tb transpose [2][64][1024] -> [2][1024][64]   (q,k)
// [6656,6668)   bias concat
// [6668]        low_bias: biasN[3072+j] = dot(b, ta[:,j])  (fp32 sources)
// =====================================================================
__global__ __launch_bounds__(256) void prep(const float* __restrict__ hs, bf16_t* __restrict__ hsb,
                                            const float* __restrict__ Wq, const float* __restrict__ Wk,
                                            const float* __restrict__ Wv, const float* __restrict__ Wo,
                                            bf16_t* __restrict__ BtExt, bf16_t* __restrict__ WoT,
                                            bf16_t* __restrict__ Wqb, bf16_t* __restrict__ Wkb,
                                            const float* __restrict__ qta, const float* __restrict__ kta,
                                            bf16_t* __restrict__ qtaT, bf16_t* __restrict__ ktaT,
                                            const float* __restrict__ qtb, const float* __restrict__ ktb,
                                            bf16_t* __restrict__ qtbT, bf16_t* __restrict__ ktbT,
                                            const float* __restrict__ bq, const float* __restrict__ bk,
                                            const float* __restrict__ bv, float* __restrict__ biasN) {
  __shared__ float tile[32][33];
  const int bid = blockIdx.x, t = threadIdx.x;
  const int tx = t & 31, ty = t >> 5;

  if (bid < 2048) {  // ---- cvt ----
    int i = (bid * 256 + t) * 8;
    float4 a = *(const float4*)(hs + i);
    float4 b = *(const float4*)(hs + i + 4);
    union { bf16_t h[8]; uint4 u; } p;
    p.h[0] = (bf16_t)a.x; p.h[1] = (bf16_t)a.y; p.h[2] = (bf16_t)a.z; p.h[3] = (bf16_t)a.w;
    p.h[4] = (bf16_t)b.x; p.h[5] = (bf16_t)b.y; p.h[6] = (bf16_t)b.z; p.h[7] = (bf16_t)b.w;
    *(uint4*)(hsb + i) = p.u;
  } else if (bid < 6144) {  // ---- weight transposes ----
    int r = bid - 2048, z = r >> 10, r10 = r & 1023;
    int bx = (r10 & 31) * 32, by = (r10 >> 5) * 32;
    const float* src = z == 0 ? Wq : z == 1 ? Wk : z == 2 ? Wv : Wo;
    bf16_t* dst = z == 3 ? WoT : BtExt + (size_t)z * 1048576;
    bf16_t* sd = z == 0 ? Wqb : z == 1 ? Wkb : nullptr;
#pragma unroll
    for (int i = 0; i < 4; ++i) {
      float v = src[(size_t)(by + ty + i * 8) * 1024 + bx + tx];
      tile[ty + i * 8][tx] = v;
      if (sd) sd[(size_t)(by + ty + i * 8) * 1024 + bx + tx] = (bf16_t)v;
    }
    __syncthreads();
#pragma unroll
    for (int i = 0; i < 4; ++i)
      dst[(size_t)(bx + ty + i * 8) * 1024 + by + tx] = (bf16_t)tile[tx][ty + i * 8];
  } else if (bid < 6400) {  // ---- ta: [1024][64] -> [64][1024], 4 slices ----
    int r = bid - 6144, z = r >> 6, r6 = r & 63;
    int bx = (r6 & 1) * 32, by = (r6 >> 1) * 32;
    const float* src = ((z >> 1) ? kta : qta) + (size_t)(z & 1) * 65536;
    bf16_t* dst = ((z >> 1) ? ktaT : qtaT) + (size_t)(z & 1) * 65536;
#pragma unroll
    for (int i = 0; i < 4; ++i)
      tile[ty + i * 8][tx] = src[(size_t)(by + ty + i * 8) * 64 + bx + tx];
    __syncthreads();
#pragma unroll
    for (int i = 0; i < 4; ++i)
      dst[(size_t)(bx + ty + i * 8) * 1024 + by + tx] = (bf16_t)tile[tx][ty + i * 8];
  } else if (bid < 6656) {  // ---- tb: [64][1024] -> [1024][64], 4 slices ----
    int r = bid - 6400, z = r >> 6, r6 = r & 63;
    int bx = (r6 & 31) * 32, by = (r6 >> 5) * 32;
    const float* src = ((z >> 1) ? ktb : qtb) + (size_t)(z & 1) * 65536;
    bf16_t* dst = ((z >> 1) ? ktbT : qtbT) + (size_t)(z & 1) * 65536;
#pragma unroll
    for (int i = 0; i < 4; ++i)
      tile[ty + i * 8][tx] = src[(size_t)(by + ty + i * 8) * 1024 + bx + tx];
    __syncthreads();
#pragma unroll
    for (int i = 0; i < 4; ++i)
      dst[(size_t)(bx + ty + i * 8) * 64 + by + tx] = (bf16_t)tile[tx][ty + i * 8];
  } else if (bid < 6668) {  // ---- bias concat ----
    int i = (bid - 6656) * 256 + t;
    biasN[i] = (i < 1024) ? bq[i] : (i < 2048 ? bk[i - 1024] : bv[i - 2048]);
  } else {  // ---- low bias ----
    int j = t;
    const float* b = (j < 128) ? bq : bk;
    const float* ta = ((j < 128) ? qta : kta) + (size_t)((j >> 6) & 1) * 65536;
    int rr = j & 63;
    float s = 0.f;
    for (int h = 0; h < 1024; ++h) s += b[h] * ta[(size_t)h * 64 + rr];
    biasN[3072 + j] = s;
  }
}

// =====================================================================
// 128x128 async GEMM core (m97 structure)
// =====================================================================
template <typename OutT>
static __device__ __forceinline__ void gemm_core_async(const bf16_t* __restrict__ A, int lda,
                                                       const bf16_t* __restrict__ Bt, int ldb,
                                                       OutT* __restrict__ C, int ldc,
                                                       const float* __restrict__ bias, int K,
                                                       int bx, int by) {
  __shared__ bf16_t As[128][32];
  __shared__ bf16_t Bs[128][32];
  const int m0 = by * 128, n0 = bx * 128;
  const int t = threadIdx.x, w = t >> 6, lane = t & 63;
  const int wm = (w >> 1) * 64, wn = (w & 1) * 64;
  const int quad = lane >> 4, l16 = lane & 15;
  const int sra = lane >> 2, sca = (lane & 3) * 8;
  const bf16_t* Ag0 = A + (size_t)(m0 + w * 16 + sra) * lda + sca;
  const bf16_t* Ag1 = A + (size_t)(m0 + 64 + w * 16 + sra) * lda + sca;
  const bf16_t* Bg0 = Bt + (size_t)(n0 + w * 16 + sra) * ldb + sca;
  const bf16_t* Bg1 = Bt + (size_t)(n0 + 64 + w * 16 + sra) * ldb + sca;
  bf16_t* la0 = &As[0][0] + w * 512;
  bf16_t* la1 = &As[0][0] + 2048 + w * 512;
  bf16_t* lb0 = &Bs[0][0] + w * 512;
  bf16_t* lb1 = &Bs[0][0] + 2048 + w * 512;

  f32x4 acc[4][4] = {};
  for (int k0 = 0; k0 < K; k0 += 32) {
    __syncthreads();
    async_cp16(Ag0 + k0, la0);
    async_cp16(Ag1 + k0, la1);
    async_cp16(Bg0 + k0, lb0);
    async_cp16(Bg1 + k0, lb1);
    __syncthreads();
    bf16x8 af[4], bfr[4];
#pragma unroll
    for (int i = 0; i < 4; ++i)
      af[i] = *(const bf16x8*)&As[wm + i * 16 + l16][quad * 8];
#pragma unroll
    for (int j = 0; j < 4; ++j)
      bfr[j] = *(const bf16x8*)&Bs[wn + j * 16 + l16][quad * 8];
#pragma unroll
    for (int i = 0; i < 4; ++i)
#pragma unroll
      for (int j = 0; j < 4; ++j)
        acc[i][j] = __builtin_amdgcn_mfma_f32_16x16x32_bf16(af[i], bfr[j], acc[i][j], 0, 0, 0);
  }
#pragma unroll
  for (int i = 0; i < 4; ++i) {
    int row = m0 + wm + i * 16 + quad * 4;
#pragma unroll
    for (int j = 0; j < 4; ++j) {
      int col = n0 + wn + j * 16 + l16;
      float bv = bias ? bias[col] : 0.f;
#pragma unroll
      for (int r = 0; r < 4; ++r)
        st_out(&C[(size_t)(row + r) * ldc + col], acc[i][j][r] + bv);
    }
  }
}

// 64x128 variant: better block-count for small-M / small-N cases
template <typename OutT>
static __device__ __forceinline__ void gemm_core_async64(const bf16_t* __restrict__ A, int lda,
                                                         const bf16_t* __restrict__ Bt, int ldb,
                                                         OutT* __restrict__ C, int ldc,
                                                         const float* __restrict__ bias, int K,
                                                         int bx, int by) {
  __shared__ bf16_t As[64][32];
  __shared__ bf16_t Bs[128][32];
  const int m0 = by * 64, n0 = bx * 128;
  const int t = threadIdx.x, w = t >> 6, lane = t & 63;
  const int wm = (w >> 1) * 32, wn = (w & 1) * 64;
  const int quad = lane >> 4, l16 = lane & 15;
  const int sra = lane >> 2, sca = (lane & 3) * 8;
  const bf16_t* Ag0 = A + (size_t)(m0 + w * 16 + sra) * lda + sca;
  const bf16_t* Bg0 = Bt + (size_t)(n0 + w * 16 + sra) * ldb + sca;
  const bf16_t* Bg1 = Bt + (size_t)(n0 + 64 + w * 16 + sra) * ldb + sca;
  bf16_t* la0 = &As[0][0] + w * 512;
  bf16_t* lb0 = &Bs[0][0] + w * 512;
  bf16_t* lb1 = &Bs[0][0] + 2048 + w * 512;

  f32x4 acc[2][4] = {};
  for (int k0 = 0; k0 < K; k0 += 32) {
    __syncthreads();
    async_cp16(Ag0 + k0, la0);
    async_cp16(Bg0 + k0, lb0);
    async_cp16(Bg1 + k0, lb1);
    __syncthreads();
    bf16x8 af[2], bfr[4];
#pragma unroll
    for (int i = 0; i < 2; ++i)
      af[i] = *(const bf16x8*)&As[wm + i * 16 + l16][quad * 8];
#pragma unroll
    for (int j = 0; j < 4; ++j)
      bfr[j] = *(const bf16x8*)&Bs[wn + j * 16 + l16][quad * 8];
#pragma unroll
    for (int i = 0; i < 2; ++i)
#pragma unroll
      for (int j = 0; j < 4; ++j)
        acc[i][j] = __builtin_amdgcn_mfma_f32_16x16x32_bf16(af[i], bfr[j], acc[i][j], 0, 0, 0);
  }
#pragma unroll
  for (int i = 0; i < 2; ++i) {
    int row = m0 + wm + i * 16 + quad * 4;
#pragma unroll
    for (int j = 0; j < 4; ++j) {
      int col = n0 + wn + j * 16 + l16;
      float bv = bias ? bias[col] : 0.f;
#pragma unroll
      for (int r = 0; r < 4; ++r)
        st_out(&C[(size_t)(row + r) * ldc + col], acc[i][j][r] + bv);
    }
  }
}

__global__ __launch_bounds__(256) void gemm_qkv(const bf16_t* __restrict__ A,
                                                const bf16_t* __restrict__ Bt,
                                                bf16_t* __restrict__ C,
                                                const float* __restrict__ biasN) {
  gemm_core_async<bf16_t>(A, 1024, Bt, 1024, C, 3328, biasN, 1024, blockIdx.x, blockIdx.y);
}

__global__ __launch_bounds__(256) void gemm_out(const bf16_t* __restrict__ A,
                                                const bf16_t* __restrict__ Bt,
                                                float* __restrict__ C,
                                                const float* __restrict__ bo) {
  gemm_core_async64<float>(A, 1024, Bt, 1024, C, 1024, bo, 1024, blockIdx.x, blockIdx.y);
}

__global__ __launch_bounds__(256) void gemm_wta(const bf16_t* __restrict__ qtaT,
                                                const bf16_t* __restrict__ ktaT,
                                                const bf16_t* __restrict__ Wqb,
                                                const bf16_t* __restrict__ Wkb,
                                                bf16_t* __restrict__ BtExt) {
  int z = blockIdx.z;
  gemm_core_async64<bf16_t>(z ? ktaT : qtaT, 1024, z ? Wkb : Wqb, 1024,
                            BtExt + (size_t)(3072 + z * 128) * 1024, 1024,
                            nullptr, 1024, blockIdx.x, blockIdx.y);
}

// =====================================================================
// fused torsion + q pre-scale by log2(e)/8
// =====================================================================
__global__ __launch_bounds__(256) void lin_torsion_fused(const bf16_t* __restrict__ qtbT,
                                                         const bf16_t* __restrict__ ktbT,
                                                         bf16_t* __restrict__ qkv,
                                                         const float* __restrict__ coupling) {
  __shared__ bf16_t As[128][136];
  __shared__ bf16_t Bs0[128][72];
  __shared__ bf16_t Bs1[128][72];
  const int z = blockIdx.z;
  const bf16_t* Low = qkv + 3072 + z * 128;
  const bf16_t* Tb = z ? ktbT : qtbT;
  bf16_t* X = qkv + z * 1024;

  const int m0 = blockIdx.y * 128, n0 = blockIdx.x * 128;
  const int t = threadIdx.x, w = t >> 6, lane = t & 63;
  const int wm = (w >> 1) * 64, wn = (w & 1) * 64;
  const int quad = lane >> 4, l16 = lane & 15;

  {
    const int sr = t >> 1, sc = (t & 1) * 64;
    const bf16_t* Ag = Low + (size_t)(m0 + sr) * 3328 + sc;
#pragma unroll
    for (int i = 0; i < 8; ++i)
      *(float4*)&As[sr][sc + 8 * i] = *(const float4*)(Ag + 8 * i);
    const int br = t >> 1, bc = (t & 1) * 32;
    const bf16_t* Bg0 = Tb + (size_t)(n0 + br) * 64 + bc;
    const bf16_t* Bg1 = Bg0 + 65536;
#pragma unroll
    for (int i = 0; i < 4; ++i) {
      *(float4*)&Bs0[br][bc + 8 * i] = *(const float4*)(Bg0 + 8 * i);
      *(float4*)&Bs1[br][bc + 8 * i] = *(const float4*)(Bg1 + 8 * i);
    }
  }
  __syncthreads();

  f32x4 acc0[4][4] = {}, acc1[4][4] = {};
#pragma unroll
  for (int ks = 0; ks < 2; ++ks) {
    bf16x8 a0[4], a1[4];
#pragma unroll
    for (int i = 0; i < 4; ++i) {
      a0[i] = *(const bf16x8*)&As[wm + i * 16 + l16][ks * 32 + quad * 8];
      a1[i] = *(const bf16x8*)&As[wm + i * 16 + l16][64 + ks * 32 + quad * 8];
    }
#pragma unroll
    for (int j = 0; j < 4; ++j) {
      bf16x8 b0 = *(const bf16x8*)&Bs0[wn + j * 16 + l16][ks * 32 + quad * 8];
      bf16x8 b1 = *(const bf16x8*)&Bs1[wn + j * 16 + l16][ks * 32 + quad * 8];
#pragma unroll
      for (int i = 0; i < 4; ++i) {
        acc0[i][j] = __builtin_amdgcn_mfma_f32_16x16x32_bf16(a0[i], b0, acc0[i][j], 0, 0, 0);
        acc1[i][j] = __builtin_amdgcn_mfma_f32_16x16x32_bf16(a1[i], b1, acc1[i][j], 0, 0, 0);
      }
    }
  }

  const float PI2 = 6.283185307179586f;
  const float sig = 1.f / (1.f + __expf(-coupling[0]));
  const float scale = z ? 1.f : 0.1803368801111204f;
#pragma unroll
  for (int i = 0; i < 4; ++i) {
#pragma unroll
    for (int j = 0; j < 4; ++j) {
#pragma unroll
      for (int r = 0; r < 4; ++r) {
        int row = m0 + wm + i * 16 + quad * 4 + r;
        int col = n0 + wn + j * 16 + l16;
        size_t idx = (size_t)row * 3328 + col;
        float l1 = acc0[i][j][r], l2 = acc1[i][j][r];
        float corr = __sinf(PI2 * l1) * l1 + __sinf(2.f * PI2 * l2) * l2 * 0.5f;
        X[idx] = (bf16_t)(((float)X[idx] + sig * corr) * scale);
      }
    }
  }
}

// =====================================================================
// Flash attention v5: key-split x2 (grid.z), register-resident P via key
// permutation, conflict-free VT (3-bit row-XOR col swizzle), partial O
// (bf16) + partial l (f32) to workspace; combine kernel finishes.
// =====================================================================
__global__ __launch_bounds__(256, 4) void flash_attn(const bf16_t* __restrict__ qkv,
                                                     bf16_t* __restrict__ Op0,
                                                     bf16_t* __restrict__ Op1,
                                                     float* __restrict__ Lp) {
  constexpr int LD = 3328, SEQ = 2048;
  const int qb = blockIdx.x, bh = blockIdx.y, ks2 = blockIdx.z;
  const int b = bh >> 4, h = bh & 15;
  const size_t base = (size_t)b * SEQ * LD + h * 64;
  const bf16_t* Qg = qkv + base;
  const bf16_t* Kg = qkv + base + 1024;
  const bf16_t* Vg = qkv + base + 2048;

  __shared__ __align__(16) unsigned char smem[29696];
  bf16_t(*VT)[136] = (bf16_t(*)[136])smem;   // [64][136] loop-live
  float* LDSo = (float*)smem;                // [256][24] f32, epilogue
  float* Lred = (float*)(smem + 24576);      // [1024] f32, epilogue

  const int t = threadIdx.x, w = t >> 6, lane = t & 63;
  const int kw = w >> 1, qw = w & 1;
  const int quad = lane >> 4, l16 = lane & 15;
  const int q0 = qb * 128;
  const int kbase = ks2 * 1024;

  // ---- Q fragments direct from global ----
  bf16x8 qf[4][2];
  {
    const bf16_t* Qrow = Qg + (size_t)(q0 + qw * 64 + l16) * LD + quad * 8;
#pragma unroll
    for (int nf = 0; nf < 4; ++nf)
#pragma unroll
      for (int ks = 0; ks < 2; ++ks)
        qf[nf][ks] = *(const bf16x8*)(Qrow + (size_t)(nf * 16) * LD + ks * 32);
  }

  f32x4 o[4][4] = {};
  float l_part[4] = {0.f, 0.f, 0.f, 0.f};

  // V staging: thread -> keys vg*4..+3, channels vcb..vcb+7
  const int vg = t >> 3, vcb = (t & 7) * 8;
  // key-slot permutation (PV B-fragment order) + bank swizzle by row
  const int colb = (((vg >> 3) << 5) | ((vg & 3) << 3) | (((vg >> 2) & 1) << 2)) ^ ((t & 7) << 3);
  const bf16_t* Vbase = Vg + (size_t)(vg * 4) * LD + vcb;
  const bf16_t* Krow = Kg + (size_t)(kw * 64 + l16) * LD + quad * 8;

  for (int k0 = kbase; k0 < kbase + 1024; k0 += 128) {
    __syncthreads();  // prev-iter vf reads done
    {
      const bf16_t* vsrc = Vbase + (size_t)k0 * LD;
      union { float4 f; bf16_t h[8]; } vr[4];
#pragma unroll
      for (int kk = 0; kk < 4; ++kk)
        vr[kk].f = *(const float4*)(vsrc + (size_t)kk * LD);
#pragma unroll
      for (int cc = 0; cc < 8; ++cc) {
        union { bf16_t h[4]; uint2 u; } pk;
#pragma unroll
        for (int kk = 0; kk < 4; ++kk) pk.h[kk] = vr[kk].h[cc];
        *(uint2*)&VT[vcb + cc][colb] = pk.u;
      }
    }
    bf16x8 kf[4][2];
#pragma unroll
    for (int jk = 0; jk < 4; ++jk)
#pragma unroll
      for (int ks = 0; ks < 2; ++ks)
        kf[jk][ks] = *(const bf16x8*)(Krow + (size_t)(k0 + jk * 16) * LD + ks * 32);
    __syncthreads();  // VT ready

    f32x4 st[4][4] = {};
#pragma unroll
    for (int ks = 0; ks < 2; ++ks)
#pragma unroll
      for (int jk = 0; jk < 4; ++jk)
#pragma unroll
        for (int nf = 0; nf < 4; ++nf)
          st[jk][nf] = __builtin_amdgcn_mfma_f32_16x16x32_bf16(kf[jk][ks], qf[nf][ks], st[jk][nf], 0, 0, 0);

    bf16x8 Pp[2][4];
#pragma unroll
    for (int g = 0; g < 2; ++g)
#pragma unroll
      for (int nf = 0; nf < 4; ++nf) {
        union { bf16_t h[8]; bf16x8 v; } ph;
#pragma unroll
        for (int b2 = 0; b2 < 2; ++b2)
#pragma unroll
          for (int r = 0; r < 4; ++r) {
            float p = exp2f(st[g * 2 + b2][nf][r]);
            l_part[nf] += p;
            ph.h[b2 * 4 + r] = (bf16_t)p;
          }
        Pp[g][nf] = ph.v;
      }

#pragma unroll
    for (int g = 0; g < 2; ++g) {
      bf16x8 vf[4];
#pragma unroll
      for (int jd = 0; jd < 4; ++jd) {
        int row = jd * 16 + l16;
        int col = (kw * 64 + g * 32 + quad * 8) ^ ((((row >> 3) & 7)) << 3);
        vf[jd] = *(const bf16x8*)&VT[row][col];
      }
#pragma unroll
      for (int jd = 0; jd < 4; ++jd)
#pragma unroll
        for (int nf = 0; nf < 4; ++nf)
          o[jd][nf] = __builtin_amdgcn_mfma_f32_16x16x32_bf16(vf[jd], Pp[g][nf], o[jd][nf], 0, 0, 0);
    }
  }

  // ---- epilogue: reduce partial l and O across kw/quad, store partials ----
  __syncthreads();
#pragma unroll
  for (int nf = 0; nf < 4; ++nf)
    Lred[((kw * 2 + qw) * 4 + quad) * 64 + nf * 16 + l16] = l_part[nf];
  __syncthreads();
  if (t < 128) {
    int qw2 = t >> 6, ql = t & 63;
    float s = 0.f;
#pragma unroll
    for (int kw2 = 0; kw2 < 2; ++kw2)
#pragma unroll
      for (int qd = 0; qd < 4; ++qd)
        s += Lred[((kw2 * 2 + qw2) * 4 + qd) * 64 + ql];
    Lp[(size_t)((ks2 * 2 + b) * 16 + h) * 2048 + q0 + t] = s;
  }
  __syncthreads();

  bf16_t* Op = ks2 ? Op1 : Op0;
  const int rq = t >> 1, rc0 = (t & 1) * 8;
#pragma unroll
  for (int jd = 0; jd < 4; ++jd) {
#pragma unroll
    for (int nf = 0; nf < 4; ++nf)
      *(f32x4*)&LDSo[(size_t)(kw * 128 + qw * 64 + nf * 16 + l16) * 24 + quad * 4] = o[jd][nf];
    __syncthreads();
    f32x4 a0 = *(const f32x4*)&LDSo[(size_t)rq * 24 + rc0];
    f32x4 a1 = *(const f32x4*)&LDSo[(size_t)(128 + rq) * 24 + rc0];
    f32x4 b0 = *(const f32x4*)&LDSo[(size_t)rq * 24 + rc0 + 4];
    f32x4 b1 = *(const f32x4*)&LDSo[(size_t)(128 + rq) * 24 + rc0 + 4];
    union { bf16_t h[8]; uint4 u; } pk;
#pragma unroll
    for (int r = 0; r < 4; ++r) {
      pk.h[r] = (bf16_t)(a0[r] + a1[r]);
      pk.h[4 + r] = (bf16_t)(b0[r] + b1[r]);
    }
    *(uint4*)&Op[(size_t)(b * SEQ + q0 + rq) * 1024 + h * 64 + jd * 16 + rc0] = pk.u;
    if (jd < 3) __syncthreads();
  }
}

// =====================================================================
// combine: aout = (O0 + O1) / (l0 + l1)
// =====================================================================
__global__ __launch_bounds__(256) void combine(const bf16_t* __restrict__ Op0,
                                               const bf16_t* __restrict__ Op1,
                                               const float* __restrict__ Lp,
                                               bf16_t* __restrict__ aout) {
  int gid = blockIdx.x * 256 + threadIdx.x;
  int tok = gid >> 7, c8 = (gid & 127) * 8;
  int b = tok >> 11, s = tok & 2047, h = c8 >> 6;
  float l = Lp[(size_t)(b * 16 + h) * 2048 + s] + Lp[(size_t)((2 + b) * 16 + h) * 2048 + s];
  float inv = 1.f / l;
  union { uint4 u; bf16_t h[8]; } o0, o1, res;
  o0.u = *(const uint4*)(Op0 + (size_t)tok * 1024 + c8);
  o1.u = *(const uint4*)(Op1 + (size_t)tok * 1024 + c8);
#pragma unroll
  for (int r = 0; r < 8; ++r)
    res.h[r] = (bf16_t)(((float)o0.h[r] + (float)o1.h[r]) * inv);
  *(uint4*)(aout + (size_t)tok * 1024 + c8) = res.u;
}

// =====================================================================
// host launch
// =====================================================================
extern "C" void kernel_launch(void* const* d_in, const int* in_sizes, int n_in,
                              void* d_out, int out_size, void* d_ws, size_t ws_size,
                              hipStream_t stream) {
  const float* hs   = (const float*)d_in[0];
  const float* Wq   = (const float*)d_in[1];
  const float* bq   = (const float*)d_in[2];
  const float* Wk   = (const float*)d_in[3];
  const float* bk   = (const float*)d_in[4];
  const float* Wv   = (const float*)d_in[5];
  const float* bv   = (const float*)d_in[6];
  const float* Wo   = (const float*)d_in[7];
  const float* bo   = (const float*)d_in[8];
  const float* qta  = (const float*)d_in[9];
  const float* qtb  = (const float*)d_in[10];
  const float* kta  = (const float*)d_in[11];
  const float* ktb  = (const float*)d_in[12];
  const float* coup = (const float*)d_in[13];
  float* out = (float*)d_out;

  uint8_t* ws = (uint8_t*)d_ws;
  // [0, 8.39M): hsb (dead after gemm_qkv) -> Opart0
  // [8.39M, 16.78M): BtExt 6.82M (dead after gemm_qkv) -> Opart1
  bf16_t* hsb   = (bf16_t*)(ws);
  bf16_t* Op0   = (bf16_t*)(ws);
  bf16_t* BtExt = (bf16_t*)(ws + 8388608);
  bf16_t* Op1   = (bf16_t*)(ws + 8388608);
  bf16_t* WoT   = (bf16_t*)(ws + 16777216);   // 2 MB
  float*  biasN = (float*)(ws + 18874368);    // 16 KB
  bf16_t* qkv   = (bf16_t*)(ws + 18890752);   // [4096][3328] 27.3 MB
  bf16_t* aout  = (bf16_t*)(ws + 46153728);   // 8.39 MB; prep scratch overlays:
  bf16_t* Wqb   = (bf16_t*)(ws + 46153728);   //   2 MB (dead after gemm_wta)
  bf16_t* Wkb   = (bf16_t*)(ws + 48250880);   //   2 MB
  bf16_t* qtaT  = (bf16_t*)(ws + 50348032);   //   256 KB
  bf16_t* ktaT  = (bf16_t*)(ws + 50610176);   //   256 KB
  bf16_t* qtbT  = (bf16_t*)(ws + 50872320);   //   256 KB (dead after lin_torsion)
  bf16_t* ktbT  = (bf16_t*)(ws + 51134464);   //   256 KB
  float*  Lp    = (float*)(ws + 54542336);    // 512 KB, end 55066624

  dim3 b256(256);

  prep<<<6669, b256, 0, stream>>>(hs, hsb, Wq, Wk, Wv, Wo, BtExt, WoT, Wqb, Wkb,
                                  qta, kta, qtaT, ktaT, qtb, ktb, qtbT, ktbT,
                                  bq, bk, bv, biasN);
  gemm_wta<<<dim3(8, 2, 2), b256, 0, stream>>>(qtaT, ktaT, Wqb, Wkb, BtExt);
  gemm_qkv<<<dim3(26, 32), b256, 0, stream>>>(hsb, BtExt, qkv, biasN);
  lin_torsion_fused<<<dim3(8, 32, 2), b256, 0, stream>>>(qtbT, ktbT, qkv, coup);
  flash_attn<<<dim3(16, 32, 2), b256, 0, stream>>>(qkv, Op0, Op1, Lp);
  combine<<<2048, b256, 0, stream>>>(Op0, Op1, Lp, aout);
  gemm_out<<<dim3(8, 64), b256, 0, stream>>>(aout, WoT, out, bo);
}

// Round 6
// 383.474 us; speedup vs baseline: 1.1505x; 1.1505x over previous
//
#include <hip/hip_runtime.h>
#include <hip/hip_bf16.h>
#include <cstdint>
#include <cstddef>

typedef __bf16 bf16_t;
typedef __bf16 bf16x8 __attribute__((ext_vector_type(8)));
typedef float f32x4 __attribute__((ext_vector_type(4)));

static __device__ __forceinline__ void st_out(float* p, float v) { *p = v; }
static __device__ __forceinline__ void st_out(bf16_t* p, float v) { *p = (bf16_t)v; }

static __device__ __forceinline__ void async_cp16(const bf16_t* g, bf16_t* l) {
  __builtin_amdgcn_global_load_lds(
      (const __attribute__((address_space(1))) void*)g,
      (__attribute__((address_space(3))) void*)l, 16, 0, 0);
}

// =====================================================================
// prep: all setup work in ONE launch. 1D grid, block ranges:
// [0,2048) cvt hs | [2048,6144) W transposes | [6144,6400) ta^T
// [6400,6656) tb^T | [6656,6668) bias concat | [6668] low bias
// =====================================================================
__global__ __launch_bounds__(256) void prep(const float* __restrict__ hs, bf16_t* __restrict__ hsb,
                                            const float* __restrict__ Wq, const float* __restrict__ Wk,
                                            const float* __restrict__ Wv, const float* __restrict__ Wo,
                                            bf16_t* __restrict__ BtExt, bf16_t* __restrict__ WoT,
                                            bf16_t* __restrict__ Wqb, bf16_t* __restrict__ Wkb,
                                            const float* __restrict__ qta, const float* __restrict__ kta,
                                            bf16_t* __restrict__ qtaT, bf16_t* __restrict__ ktaT,
                                            const float* __restrict__ qtb, const float* __restrict__ ktb,
                                            bf16_t* __restrict__ qtbT, bf16_t* __restrict__ ktbT,
                                            const float* __restrict__ bq, const float* __restrict__ bk,
                                            const float* __restrict__ bv, float* __restrict__ biasN) {
  __shared__ float tile[32][33];
  const int bid = blockIdx.x, t = threadIdx.x;
  const int tx = t & 31, ty = t >> 5;

  if (bid < 2048) {  // ---- cvt ----
    int i = (bid * 256 + t) * 8;
    float4 a = *(const float4*)(hs + i);
    float4 b = *(const float4*)(hs + i + 4);
    union { bf16_t h[8]; uint4 u; } p;
    p.h[0] = (bf16_t)a.x; p.h[1] = (bf16_t)a.y; p.h[2] = (bf16_t)a.z; p.h[3] = (bf16_t)a.w;
    p.h[4] = (bf16_t)b.x; p.h[5] = (bf16_t)b.y; p.h[6] = (bf16_t)b.z; p.h[7] = (bf16_t)b.w;
    *(uint4*)(hsb + i) = p.u;
  } else if (bid < 6144) {  // ---- weight transposes ----
    int r = bid - 2048, z = r >> 10, r10 = r & 1023;
    int bx = (r10 & 31) * 32, by = (r10 >> 5) * 32;
    const float* src = z == 0 ? Wq : z == 1 ? Wk : z == 2 ? Wv : Wo;
    bf16_t* dst = z == 3 ? WoT : BtExt + (size_t)z * 1048576;
    bf16_t* sd = z == 0 ? Wqb : z == 1 ? Wkb : nullptr;
#pragma unroll
    for (int i = 0; i < 4; ++i) {
      float v = src[(size_t)(by + ty + i * 8) * 1024 + bx + tx];
      tile[ty + i * 8][tx] = v;
      if (sd) sd[(size_t)(by + ty + i * 8) * 1024 + bx + tx] = (bf16_t)v;
    }
    __syncthreads();
#pragma unroll
    for (int i = 0; i < 4; ++i)
      dst[(size_t)(bx + ty + i * 8) * 1024 + by + tx] = (bf16_t)tile[tx][ty + i * 8];
  } else if (bid < 6400) {  // ---- ta: [1024][64] -> [64][1024] ----
    int r = bid - 6144, z = r >> 6, r6 = r & 63;
    int bx = (r6 & 1) * 32, by = (r6 >> 1) * 32;
    const float* src = ((z >> 1) ? kta : qta) + (size_t)(z & 1) * 65536;
    bf16_t* dst = ((z >> 1) ? ktaT : qtaT) + (size_t)(z & 1) * 65536;
#pragma unroll
    for (int i = 0; i < 4; ++i)
      tile[ty + i * 8][tx] = src[(size_t)(by + ty + i * 8) * 64 + bx + tx];
    __syncthreads();
#pragma unroll
    for (int i = 0; i < 4; ++i)
      dst[(size_t)(bx + ty + i * 8) * 1024 + by + tx] = (bf16_t)tile[tx][ty + i * 8];
  } else if (bid < 6656) {  // ---- tb: [64][1024] -> [1024][64] ----
    int r = bid - 6400, z = r >> 6, r6 = r & 63;
    int bx = (r6 & 31) * 32, by = (r6 >> 5) * 32;
    const float* src = ((z >> 1) ? ktb : qtb) + (size_t)(z & 1) * 65536;
    bf16_t* dst = ((z >> 1) ? ktbT : qtbT) + (size_t)(z & 1) * 65536;
#pragma unroll
    for (int i = 0; i < 4; ++i)
      tile[ty + i * 8][tx] = src[(size_t)(by + ty + i * 8) * 1024 + bx + tx];
    __syncthreads();
#pragma unroll
    for (int i = 0; i < 4; ++i)
      dst[(size_t)(bx + ty + i * 8) * 64 + by + tx] = (bf16_t)tile[tx][ty + i * 8];
  } else if (bid < 6668) {  // ---- bias concat ----
    int i = (bid - 6656) * 256 + t;
    biasN[i] = (i < 1024) ? bq[i] : (i < 2048 ? bk[i - 1024] : bv[i - 2048]);
  } else {  // ---- low bias ----
    int j = t;
    const float* b = (j < 128) ? bq : bk;
    const float* ta = ((j < 128) ? qta : kta) + (size_t)((j >> 6) & 1) * 65536;
    int rr = j & 63;
    float s = 0.f;
    for (int h = 0; h < 1024; ++h) s += b[h] * ta[(size_t)h * 64 + rr];
    biasN[3072 + j] = s;
  }
}

// =====================================================================
// 128x128 async GEMM core (m97 structure)
// =====================================================================
template <typename OutT>
static __device__ __forceinline__ void gemm_core_async(const bf16_t* __restrict__ A, int lda,
                                                       const bf16_t* __restrict__ Bt, int ldb,
                                                       OutT* __restrict__ C, int ldc,
                                                       const float* __restrict__ bias, int K,
                                                       int bx, int by) {
  __shared__ bf16_t As[128][32];
  __shared__ bf16_t Bs[128][32];
  const int m0 = by * 128, n0 = bx * 128;
  const int t = threadIdx.x, w = t >> 6, lane = t & 63;
  const int wm = (w >> 1) * 64, wn = (w & 1) * 64;
  const int quad = lane >> 4, l16 = lane & 15;
  const int sra = lane >> 2, sca = (lane & 3) * 8;
  const bf16_t* Ag0 = A + (size_t)(m0 + w * 16 + sra) * lda + sca;
  const bf16_t* Ag1 = A + (size_t)(m0 + 64 + w * 16 + sra) * lda + sca;
  const bf16_t* Bg0 = Bt + (size_t)(n0 + w * 16 + sra) * ldb + sca;
  const bf16_t* Bg1 = Bt + (size_t)(n0 + 64 + w * 16 + sra) * ldb + sca;
  bf16_t* la0 = &As[0][0] + w * 512;
  bf16_t* la1 = &As[0][0] + 2048 + w * 512;
  bf16_t* lb0 = &Bs[0][0] + w * 512;
  bf16_t* lb1 = &Bs[0][0] + 2048 + w * 512;

  f32x4 acc[4][4] = {};
  for (int k0 = 0; k0 < K; k0 += 32) {
    __syncthreads();
    async_cp16(Ag0 + k0, la0);
    async_cp16(Ag1 + k0, la1);
    async_cp16(Bg0 + k0, lb0);
    async_cp16(Bg1 + k0, lb1);
    __syncthreads();
    bf16x8 af[4], bfr[4];
#pragma unroll
    for (int i = 0; i < 4; ++i)
      af[i] = *(const bf16x8*)&As[wm + i * 16 + l16][quad * 8];
#pragma unroll
    for (int j = 0; j < 4; ++j)
      bfr[j] = *(const bf16x8*)&Bs[wn + j * 16 + l16][quad * 8];
#pragma unroll
    for (int i = 0; i < 4; ++i)
#pragma unroll
      for (int j = 0; j < 4; ++j)
        acc[i][j] = __builtin_amdgcn_mfma_f32_16x16x32_bf16(af[i], bfr[j], acc[i][j], 0, 0, 0);
  }
#pragma unroll
  for (int i = 0; i < 4; ++i) {
    int row = m0 + wm + i * 16 + quad * 4;
#pragma unroll
    for (int j = 0; j < 4; ++j) {
      int col = n0 + wn + j * 16 + l16;
      float bv = bias ? bias[col] : 0.f;
#pragma unroll
      for (int r = 0; r < 4; ++r)
        st_out(&C[(size_t)(row + r) * ldc + col], acc[i][j][r] + bv);
    }
  }
}

// 64x128 variant
template <typename OutT>
static __device__ __forceinline__ void gemm_core_async64(const bf16_t* __restrict__ A, int lda,
                                                         const bf16_t* __restrict__ Bt, int ldb,
                                                         OutT* __restrict__ C, int ldc,
                                                         const float* __restrict__ bias, int K,
                                                         int bx, int by) {
  __shared__ bf16_t As[64][32];
  __shared__ bf16_t Bs[128][32];
  const int m0 = by * 64, n0 = bx * 128;
  const int t = threadIdx.x, w = t >> 6, lane = t & 63;
  const int wm = (w >> 1) * 32, wn = (w & 1) * 64;
  const int quad = lane >> 4, l16 = lane & 15;
  const int sra = lane >> 2, sca = (lane & 3) * 8;
  const bf16_t* Ag0 = A + (size_t)(m0 + w * 16 + sra) * lda + sca;
  const bf16_t* Bg0 = Bt + (size_t)(n0 + w * 16 + sra) * ldb + sca;
  const bf16_t* Bg1 = Bt + (size_t)(n0 + 64 + w * 16 + sra) * ldb + sca;
  bf16_t* la0 = &As[0][0] + w * 512;
  bf16_t* lb0 = &Bs[0][0] + w * 512;
  bf16_t* lb1 = &Bs[0][0] + 2048 + w * 512;

  f32x4 acc[2][4] = {};
  for (int k0 = 0; k0 < K; k0 += 32) {
    __syncthreads();
    async_cp16(Ag0 + k0, la0);
    async_cp16(Bg0 + k0, lb0);
    async_cp16(Bg1 + k0, lb1);
    __syncthreads();
    bf16x8 af[2], bfr[4];
#pragma unroll
    for (int i = 0; i < 2; ++i)
      af[i] = *(const bf16x8*)&As[wm + i * 16 + l16][quad * 8];
#pragma unroll
    for (int j = 0; j < 4; ++j)
      bfr[j] = *(const bf16x8*)&Bs[wn + j * 16 + l16][quad * 8];
#pragma unroll
    for (int i = 0; i < 2; ++i)
#pragma unroll
      for (int j = 0; j < 4; ++j)
        acc[i][j] = __builtin_amdgcn_mfma_f32_16x16x32_bf16(af[i], bfr[j], acc[i][j], 0, 0, 0);
  }
#pragma unroll
  for (int i = 0; i < 2; ++i) {
    int row = m0 + wm + i * 16 + quad * 4;
#pragma unroll
    for (int j = 0; j < 4; ++j) {
      int col = n0 + wn + j * 16 + l16;
      float bv = bias ? bias[col] : 0.f;
#pragma unroll
      for (int r = 0; r < 4; ++r)
        st_out(&C[(size_t)(row + r) * ldc + col], acc[i][j][r] + bv);
    }
  }
}

__global__ __launch_bounds__(256) void gemm_qkv(const bf16_t* __restrict__ A,
                                                const bf16_t* __restrict__ Bt,
                                                bf16_t* __restrict__ C,
                                                const float* __restrict__ biasN) {
  gemm_core_async<bf16_t>(A, 1024, Bt, 1024, C, 3328, biasN, 1024, blockIdx.x, blockIdx.y);
}

__global__ __launch_bounds__(256) void gemm_out(const bf16_t* __restrict__ A,
                                                const bf16_t* __restrict__ Bt,
                                                float* __restrict__ C,
                                                const float* __restrict__ bo) {
  gemm_core_async64<float>(A, 1024, Bt, 1024, C, 1024, bo, 1024, blockIdx.x, blockIdx.y);
}

__global__ __launch_bounds__(256) void gemm_wta(const bf16_t* __restrict__ qtaT,
                                                const bf16_t* __restrict__ ktaT,
                                                const bf16_t* __restrict__ Wqb,
                                                const bf16_t* __restrict__ Wkb,
                                                bf16_t* __restrict__ BtExt) {
  int z = blockIdx.z;
  gemm_core_async64<bf16_t>(z ? ktaT : qtaT, 1024, z ? Wkb : Wqb, 1024,
                            BtExt + (size_t)(3072 + z * 128) * 1024, 1024,
                            nullptr, 1024, blockIdx.x, blockIdx.y);
}

// =====================================================================
// fused torsion + q pre-scale by log2(e)/8
// =====================================================================
__global__ __launch_bounds__(256) void lin_torsion_fused(const bf16_t* __restrict__ qtbT,
                                                         const bf16_t* __restrict__ ktbT,
                                                         bf16_t* __restrict__ qkv,
                                                         const float* __restrict__ coupling) {
  __shared__ bf16_t As[128][136];
  __shared__ bf16_t Bs0[128][72];
  __shared__ bf16_t Bs1[128][72];
  const int z = blockIdx.z;
  const bf16_t* Low = qkv + 3072 + z * 128;
  const bf16_t* Tb = z ? ktbT : qtbT;
  bf16_t* X = qkv + z * 1024;

  const int m0 = blockIdx.y * 128, n0 = blockIdx.x * 128;
  const int t = threadIdx.x, w = t >> 6, lane = t & 63;
  const int wm = (w >> 1) * 64, wn = (w & 1) * 64;
  const int quad = lane >> 4, l16 = lane & 15;

  {
    const int sr = t >> 1, sc = (t & 1) * 64;
    const bf16_t* Ag = Low + (size_t)(m0 + sr) * 3328 + sc;
#pragma unroll
    for (int i = 0; i < 8; ++i)
      *(float4*)&As[sr][sc + 8 * i] = *(const float4*)(Ag + 8 * i);
    const int br = t >> 1, bc = (t & 1) * 32;
    const bf16_t* Bg0 = Tb + (size_t)(n0 + br) * 64 + bc;
    const bf16_t* Bg1 = Bg0 + 65536;
#pragma unroll
    for (int i = 0; i < 4; ++i) {
      *(float4*)&Bs0[br][bc + 8 * i] = *(const float4*)(Bg0 + 8 * i);
      *(float4*)&Bs1[br][bc + 8 * i] = *(const float4*)(Bg1 + 8 * i);
    }
  }
  __syncthreads();

  f32x4 acc0[4][4] = {}, acc1[4][4] = {};
#pragma unroll
  for (int ks = 0; ks < 2; ++ks) {
    bf16x8 a0[4], a1[4];
#pragma unroll
    for (int i = 0; i < 4; ++i) {
      a0[i] = *(const bf16x8*)&As[wm + i * 16 + l16][ks * 32 + quad * 8];
      a1[i] = *(const bf16x8*)&As[wm + i * 16 + l16][64 + ks * 32 + quad * 8];
    }
#pragma unroll
    for (int j = 0; j < 4; ++j) {
      bf16x8 b0 = *(const bf16x8*)&Bs0[wn + j * 16 + l16][ks * 32 + quad * 8];
      bf16x8 b1 = *(const bf16x8*)&Bs1[wn + j * 16 + l16][ks * 32 + quad * 8];
#pragma unroll
      for (int i = 0; i < 4; ++i) {
        acc0[i][j] = __builtin_amdgcn_mfma_f32_16x16x32_bf16(a0[i], b0, acc0[i][j], 0, 0, 0);
        acc1[i][j] = __builtin_amdgcn_mfma_f32_16x16x32_bf16(a1[i], b1, acc1[i][j], 0, 0, 0);
      }
    }
  }

  const float PI2 = 6.283185307179586f;
  const float sig = 1.f / (1.f + __expf(-coupling[0]));
  const float scale = z ? 1.f : 0.1803368801111204f;
#pragma unroll
  for (int i = 0; i < 4; ++i) {
#pragma unroll
    for (int j = 0; j < 4; ++j) {
#pragma unroll
      for (int r = 0; r < 4; ++r) {
        int row = m0 + wm + i * 16 + quad * 4 + r;
        int col = n0 + wn + j * 16 + l16;
        size_t idx = (size_t)row * 3328 + col;
        float l1 = acc0[i][j][r], l2 = acc1[i][j][r];
        float corr = __sinf(PI2 * l1) * l1 + __sinf(2.f * PI2 * l2) * l2 * 0.5f;
        X[idx] = (bf16_t)(((float)X[idx] + sig * corr) * scale);
      }
    }
  }
}

// =====================================================================
// Flash attention v6 = v5 structure with the register budget restored.
// __launch_bounds__(256,3): cap 168 VGPR (body needs ~108) -> no spill;
// HW still co-schedules 4 blocks/CU (4x112 VGPR <= 512, 4x29.7KB <= 160KB).
// Key-split x2 via grid.z -> 1024 blocks. Register-resident P via key
// permutation; conflict-free VT (3-bit row-XOR swizzle, verified R5:
// conflicts 8.8M -> 2.9M).
// =====================================================================
__global__ __launch_bounds__(256, 3) void flash_attn(const bf16_t* __restrict__ qkv,
                                                     bf16_t* __restrict__ Op0,
                                                     bf16_t* __restrict__ Op1,
                                                     float* __restrict__ Lp) {
  constexpr int LD = 3328, SEQ = 2048;
  const int qb = blockIdx.x, bh = blockIdx.y, ks2 = blockIdx.z;
  const int b = bh >> 4, h = bh & 15;
  const size_t base = (size_t)b * SEQ * LD + h * 64;
  const bf16_t* Qg = qkv + base;
  const bf16_t* Kg = qkv + base + 1024;
  const bf16_t* Vg = qkv + base + 2048;

  __shared__ __align__(16) unsigned char smem[29696];
  bf16_t(*VT)[136] = (bf16_t(*)[136])smem;   // [64][136] loop-live
  float* LDSo = (float*)smem;                // [256][24] f32, epilogue
  float* Lred = (float*)(smem + 24576);      // [1024] f32, epilogue

  const int t = threadIdx.x, w = t >> 6, lane = t & 63;
  const int kw = w >> 1, qw = w & 1;
  const int quad = lane >> 4, l16 = lane & 15;
  const int q0 = qb * 128;
  const int kbase = ks2 * 1024;

  // ---- Q fragments direct from global ----
  bf16x8 qf[4][2];
  {
    const bf16_t* Qrow = Qg + (size_t)(q0 + qw * 64 + l16) * LD + quad * 8;
#pragma unroll
    for (int nf = 0; nf < 4; ++nf)
#pragma unroll
      for (int ks = 0; ks < 2; ++ks)
        qf[nf][ks] = *(const bf16x8*)(Qrow + (size_t)(nf * 16) * LD + ks * 32);
  }

  f32x4 o[4][4] = {};
  float l_part[4] = {0.f, 0.f, 0.f, 0.f};

  const int vg = t >> 3, vcb = (t & 7) * 8;
  const int colb = (((vg >> 3) << 5) | ((vg & 3) << 3) | (((vg >> 2) & 1) << 2)) ^ ((t & 7) << 3);
  const bf16_t* Vbase = Vg + (size_t)(vg * 4) * LD + vcb;
  const bf16_t* Krow = Kg + (size_t)(kw * 64 + l16) * LD + quad * 8;

  for (int k0 = kbase; k0 < kbase + 1024; k0 += 128) {
    __syncthreads();  // prev-iter vf reads done
    {
      const bf16_t* vsrc = Vbase + (size_t)k0 * LD;
      union { float4 f; bf16_t h[8]; } vr[4];
#pragma unroll
      for (int kk = 0; kk < 4; ++kk)
        vr[kk].f = *(const float4*)(vsrc + (size_t)kk * LD);
#pragma unroll
      for (int cc = 0; cc < 8; ++cc) {
        union { bf16_t h[4]; uint2 u; } pk;
#pragma unroll
        for (int kk = 0; kk < 4; ++kk) pk.h[kk] = vr[kk].h[cc];
        *(uint2*)&VT[vcb + cc][colb] = pk.u;
      }
    }
    bf16x8 kf[4][2];
#pragma unroll
    for (int jk = 0; jk < 4; ++jk)
#pragma unroll
      for (int ks = 0; ks < 2; ++ks)
        kf[jk][ks] = *(const bf16x8*)(Krow + (size_t)(k0 + jk * 16) * LD + ks * 32);
    __syncthreads();  // VT ready

    f32x4 st[4][4] = {};
#pragma unroll
    for (int ks = 0; ks < 2; ++ks)
#pragma unroll
      for (int jk = 0; jk < 4; ++jk)
#pragma unroll
        for (int nf = 0; nf < 4; ++nf)
          st[jk][nf] = __builtin_amdgcn_mfma_f32_16x16x32_bf16(kf[jk][ks], qf[nf][ks], st[jk][nf], 0, 0, 0);

    bf16x8 Pp[2][4];
#pragma unroll
    for (int g = 0; g < 2; ++g)
#pragma unroll
      for (int nf = 0; nf < 4; ++nf) {
        union { bf16_t h[8]; bf16x8 v; } ph;
#pragma unroll
        for (int b2 = 0; b2 < 2; ++b2)
#pragma unroll
          for (int r = 0; r < 4; ++r) {
            float p = exp2f(st[g * 2 + b2][nf][r]);
            l_part[nf] += p;
            ph.h[b2 * 4 + r] = (bf16_t)p;
          }
        Pp[g][nf] = ph.v;
      }

#pragma unroll
    for (int g = 0; g < 2; ++g) {
      bf16x8 vf[4];
#pragma unroll
      for (int jd = 0; jd < 4; ++jd) {
        int row = jd * 16 + l16;
        int col = (kw * 64 + g * 32 + quad * 8) ^ ((((row >> 3) & 7)) << 3);
        vf[jd] = *(const bf16x8*)&VT[row][col];
      }
#pragma unroll
      for (int jd = 0; jd < 4; ++jd)
#pragma unroll
        for (int nf = 0; nf < 4; ++nf)
          o[jd][nf] = __builtin_amdgcn_mfma_f32_16x16x32_bf16(vf[jd], Pp[g][nf], o[jd][nf], 0, 0, 0);
    }
  }

  // ---- epilogue: reduce partial l and O across kw/quad, store partials ----
  __syncthreads();
#pragma unroll
  for (int nf = 0; nf < 4; ++nf)
    Lred[((kw * 2 + qw) * 4 + quad) * 64 + nf * 16 + l16] = l_part[nf];
  __syncthreads();
  if (t < 128) {
    int qw2 = t >> 6, ql = t & 63;
    float s = 0.f;
#pragma unroll
    for (int kw2 = 0; kw2 < 2; ++kw2)
#pragma unroll
      for (int qd = 0; qd < 4; ++qd)
        s += Lred[((kw2 * 2 + qw2) * 4 + qd) * 64 + ql];
    Lp[(size_t)((ks2 * 2 + b) * 16 + h) * 2048 + q0 + t] = s;
  }
  __syncthreads();

  bf16_t* Op = ks2 ? Op1 : Op0;
  const int rq = t >> 1, rc0 = (t & 1) * 8;
#pragma unroll
  for (int jd = 0; jd < 4; ++jd) {
#pragma unroll
    for (int nf = 0; nf < 4; ++nf)
      *(f32x4*)&LDSo[(size_t)(kw * 128 + qw * 64 + nf * 16 + l16) * 24 + quad * 4] = o[jd][nf];
    __syncthreads();
    f32x4 a0 = *(const f32x4*)&LDSo[(size_t)rq * 24 + rc0];
    f32x4 a1 = *(const f32x4*)&LDSo[(size_t)(128 + rq) * 24 + rc0];
    f32x4 b0 = *(const f32x4*)&LDSo[(size_t)rq * 24 + rc0 + 4];
    f32x4 b1 = *(const f32x4*)&LDSo[(size_t)(128 + rq) * 24 + rc0 + 4];
    union { bf16_t h[8]; uint4 u; } pk;
#pragma unroll
    for (int r = 0; r < 4; ++r) {
      pk.h[r] = (bf16_t)(a0[r] + a1[r]);
      pk.h[4 + r] = (bf16_t)(b0[r] + b1[r]);
    }
    *(uint4*)&Op[(size_t)(b * SEQ + q0 + rq) * 1024 + h * 64 + jd * 16 + rc0] = pk.u;
    if (jd < 3) __syncthreads();
  }
}

// =====================================================================
// combine: aout = (O0 + O1) / (l0 + l1)
// =====================================================================
__global__ __launch_bounds__(256) void combine(const bf16_t* __restrict__ Op0,
                                               const bf16_t* __restrict__ Op1,
                                               const float* __restrict__ Lp,
                                               bf16_t* __restrict__ aout) {
  int gid = blockIdx.x * 256 + threadIdx.x;
  int tok = gid >> 7, c8 = (gid & 127) * 8;
  int b = tok >> 11, s = tok & 2047, h = c8 >> 6;
  float l = Lp[(size_t)(b * 16 + h) * 2048 + s] + Lp[(size_t)((2 + b) * 16 + h) * 2048 + s];
  float inv = 1.f / l;
  union { uint4 u; bf16_t h[8]; } o0, o1, res;
  o0.u = *(const uint4*)(Op0 + (size_t)tok * 1024 + c8);
  o1.u = *(const uint4*)(Op1 + (size_t)tok * 1024 + c8);
#pragma unroll
  for (int r = 0; r < 8; ++r)
    res.h[r] = (bf16_t)(((float)o0.h[r] + (float)o1.h[r]) * inv);
  *(uint4*)(aout + (size_t)tok * 1024 + c8) = res.u;
}

// =====================================================================
// host launch
// =====================================================================
extern "C" void kernel_launch(void* const* d_in, const int* in_sizes, int n_in,
                              void* d_out, int out_size, void* d_ws, size_t ws_size,
                              hipStream_t stream) {
  const float* hs   = (const float*)d_in[0];
  const float* Wq   = (const float*)d_in[1];
  const float* bq   = (const float*)d_in[2];
  const float* Wk   = (const float*)d_in[3];
  const float* bk   = (const float*)d_in[4];
  const float* Wv   = (const float*)d_in[5];
  const float* bv   = (const float*)d_in[6];
  const float* Wo   = (const float*)d_in[7];
  const float* bo   = (const float*)d_in[8];
  const float* qta  = (const float*)d_in[9];
  const float* qtb  = (const float*)d_in[10];
  const float* kta  = (const float*)d_in[11];
  const float* ktb  = (const float*)d_in[12];
  const float* coup = (const float*)d_in[13];
  float* out = (float*)d_out;

  uint8_t* ws = (uint8_t*)d_ws;
  bf16_t* hsb   = (bf16_t*)(ws);              // dead after gemm_qkv -> Op0
  bf16_t* Op0   = (bf16_t*)(ws);
  bf16_t* BtExt = (bf16_t*)(ws + 8388608);    // dead after gemm_qkv -> Op1
  bf16_t* Op1   = (bf16_t*)(ws + 8388608);
  bf16_t* WoT   = (bf16_t*)(ws + 16777216);   // 2 MB
  float*  biasN = (float*)(ws + 18874368);    // 16 KB
  bf16_t* qkv   = (bf16_t*)(ws + 18890752);   // [4096][3328] 27.3 MB
  bf16_t* aout  = (bf16_t*)(ws + 46153728);   // 8.39 MB; prep scratch overlays:
  bf16_t* Wqb   = (bf16_t*)(ws + 46153728);
  bf16_t* Wkb   = (bf16_t*)(ws + 48250880);
  bf16_t* qtaT  = (bf16_t*)(ws + 50348032);
  bf16_t* ktaT  = (bf16_t*)(ws + 50610176);
  bf16_t* qtbT  = (bf16_t*)(ws + 50872320);
  bf16_t* ktbT  = (bf16_t*)(ws + 51134464);
  float*  Lp    = (float*)(ws + 54542336);    // 512 KB

  dim3 b256(256);

  prep<<<6669, b256, 0, stream>>>(hs, hsb, Wq, Wk, Wv, Wo, BtExt, WoT, Wqb, Wkb,
                                  qta, kta, qtaT, ktaT, qtb, ktb, qtbT, ktbT,
                                  bq, bk, bv, biasN);
  gemm_wta<<<dim3(8, 2, 2), b256, 0, stream>>>(qtaT, ktaT, Wqb, Wkb, BtExt);
  gemm_qkv<<<dim3(26, 32), b256, 0, stream>>>(hsb, BtExt, qkv, biasN);
  lin_torsion_fused<<<dim3(8, 32, 2), b256, 0, stream>>>(qtbT, ktbT, qkv, coup);
  flash_attn<<<dim3(16, 32, 2), b256, 0, stream>>>(qkv, Op0, Op1, Lp);
  combine<<<2048, b256, 0, stream>>>(Op0, Op1, Lp, aout);
  gemm_out<<<dim3(8, 64), b256, 0, stream>>>(aout, WoT, out, bo);
}

// Round 7
// 289.844 us; speedup vs baseline: 1.5222x; 1.3230x over previous
//
#include <hip/hip_runtime.h>
#include <hip/hip_bf16.h>
#include <cstdint>
#include <cstddef>

typedef __bf16 bf16_t;
typedef __bf16 bf16x8 __attribute__((ext_vector_type(8)));
typedef float f32x4 __attribute__((ext_vector_type(4)));

static __device__ __forceinline__ void st_out(float* p, float v) { *p = v; }
static __device__ __forceinline__ void st_out(bf16_t* p, float v) { *p = (bf16_t)v; }

static __device__ __forceinline__ void async_cp16(const bf16_t* g, bf16_t* l) {
  __builtin_amdgcn_global_load_lds(
      (const __attribute__((address_space(1))) void*)g,
      (__attribute__((address_space(3))) void*)l, 16, 0, 0);
}

// =====================================================================
// prep: all setup work in ONE launch. 1D grid, block ranges:
// [0,2048) cvt hs | [2048,6144) W transposes | [6144,6400) ta^T
// [6400,6656) tb^T | [6656,6668) bias concat | [6668] low bias
// =====================================================================
__global__ __launch_bounds__(256) void prep(const float* __restrict__ hs, bf16_t* __restrict__ hsb,
                                            const float* __restrict__ Wq, const float* __restrict__ Wk,
                                            const float* __restrict__ Wv, const float* __restrict__ Wo,
                                            bf16_t* __restrict__ BtExt, bf16_t* __restrict__ WoT,
                                            bf16_t* __restrict__ Wqb, bf16_t* __restrict__ Wkb,
                                            const float* __restrict__ qta, const float* __restrict__ kta,
                                            bf16_t* __restrict__ qtaT, bf16_t* __restrict__ ktaT,
                                            const float* __restrict__ qtb, const float* __restrict__ ktb,
                                            bf16_t* __restrict__ qtbT, bf16_t* __restrict__ ktbT,
                                            const float* __restrict__ bq, const float* __restrict__ bk,
                                            const float* __restrict__ bv, float* __restrict__ biasN) {
  __shared__ float tile[32][33];
  const int bid = blockIdx.x, t = threadIdx.x;
  const int tx = t & 31, ty = t >> 5;

  if (bid < 2048) {  // ---- cvt ----
    int i = (bid * 256 + t) * 8;
    float4 a = *(const float4*)(hs + i);
    float4 b = *(const float4*)(hs + i + 4);
    union { bf16_t h[8]; uint4 u; } p;
    p.h[0] = (bf16_t)a.x; p.h[1] = (bf16_t)a.y; p.h[2] = (bf16_t)a.z; p.h[3] = (bf16_t)a.w;
    p.h[4] = (bf16_t)b.x; p.h[5] = (bf16_t)b.y; p.h[6] = (bf16_t)b.z; p.h[7] = (bf16_t)b.w;
    *(uint4*)(hsb + i) = p.u;
  } else if (bid < 6144) {  // ---- weight transposes ----
    int r = bid - 2048, z = r >> 10, r10 = r & 1023;
    int bx = (r10 & 31) * 32, by = (r10 >> 5) * 32;
    const float* src = z == 0 ? Wq : z == 1 ? Wk : z == 2 ? Wv : Wo;
    bf16_t* dst = z == 3 ? WoT : BtExt + (size_t)z * 1048576;
    bf16_t* sd = z == 0 ? Wqb : z == 1 ? Wkb : nullptr;
#pragma unroll
    for (int i = 0; i < 4; ++i) {
      float v = src[(size_t)(by + ty + i * 8) * 1024 + bx + tx];
      tile[ty + i * 8][tx] = v;
      if (sd) sd[(size_t)(by + ty + i * 8) * 1024 + bx + tx] = (bf16_t)v;
    }
    __syncthreads();
#pragma unroll
    for (int i = 0; i < 4; ++i)
      dst[(size_t)(bx + ty + i * 8) * 1024 + by + tx] = (bf16_t)tile[tx][ty + i * 8];
  } else if (bid < 6400) {  // ---- ta: [1024][64] -> [64][1024] ----
    int r = bid - 6144, z = r >> 6, r6 = r & 63;
    int bx = (r6 & 1) * 32, by = (r6 >> 1) * 32;
    const float* src = ((z >> 1) ? kta : qta) + (size_t)(z & 1) * 65536;
    bf16_t* dst = ((z >> 1) ? ktaT : qtaT) + (size_t)(z & 1) * 65536;
#pragma unroll
    for (int i = 0; i < 4; ++i)
      tile[ty + i * 8][tx] = src[(size_t)(by + ty + i * 8) * 64 + bx + tx];
    __syncthreads();
#pragma unroll
    for (int i = 0; i < 4; ++i)
      dst[(size_t)(bx + ty + i * 8) * 1024 + by + tx] = (bf16_t)tile[tx][ty + i * 8];
  } else if (bid < 6656) {  // ---- tb: [64][1024] -> [1024][64] ----
    int r = bid - 6400, z = r >> 6, r6 = r & 63;
    int bx = (r6 & 31) * 32, by = (r6 >> 5) * 32;
    const float* src = ((z >> 1) ? ktb : qtb) + (size_t)(z & 1) * 65536;
    bf16_t* dst = ((z >> 1) ? ktbT : qtbT) + (size_t)(z & 1) * 65536;
#pragma unroll
    for (int i = 0; i < 4; ++i)
      tile[ty + i * 8][tx] = src[(size_t)(by + ty + i * 8) * 1024 + bx + tx];
    __syncthreads();
#pragma unroll
    for (int i = 0; i < 4; ++i)
      dst[(size_t)(bx + ty + i * 8) * 64 + by + tx] = (bf16_t)tile[tx][ty + i * 8];
  } else if (bid < 6668) {  // ---- bias concat ----
    int i = (bid - 6656) * 256 + t;
    biasN[i] = (i < 1024) ? bq[i] : (i < 2048 ? bk[i - 1024] : bv[i - 2048]);
  } else {  // ---- low bias ----
    int j = t;
    const float* b = (j < 128) ? bq : bk;
    const float* ta = ((j < 128) ? qta : kta) + (size_t)((j >> 6) & 1) * 65536;
    int rr = j & 63;
    float s = 0.f;
    for (int h = 0; h < 1024; ++h) s += b[h] * ta[(size_t)h * 64 + rr];
    biasN[3072 + j] = s;
  }
}

// =====================================================================
// 128x128 async GEMM core (m97 structure)
// =====================================================================
template <typename OutT>
static __device__ __forceinline__ void gemm_core_async(const bf16_t* __restrict__ A, int lda,
                                                       const bf16_t* __restrict__ Bt, int ldb,
                                                       OutT* __restrict__ C, int ldc,
                                                       const float* __restrict__ bias, int K,
                                                       int bx, int by) {
  __shared__ bf16_t As[128][32];
  __shared__ bf16_t Bs[128][32];
  const int m0 = by * 128, n0 = bx * 128;
  const int t = threadIdx.x, w = t >> 6, lane = t & 63;
  const int wm = (w >> 1) * 64, wn = (w & 1) * 64;
  const int quad = lane >> 4, l16 = lane & 15;
  const int sra = lane >> 2, sca = (lane & 3) * 8;
  const bf16_t* Ag0 = A + (size_t)(m0 + w * 16 + sra) * lda + sca;
  const bf16_t* Ag1 = A + (size_t)(m0 + 64 + w * 16 + sra) * lda + sca;
  const bf16_t* Bg0 = Bt + (size_t)(n0 + w * 16 + sra) * ldb + sca;
  const bf16_t* Bg1 = Bt + (size_t)(n0 + 64 + w * 16 + sra) * ldb + sca;
  bf16_t* la0 = &As[0][0] + w * 512;
  bf16_t* la1 = &As[0][0] + 2048 + w * 512;
  bf16_t* lb0 = &Bs[0][0] + w * 512;
  bf16_t* lb1 = &Bs[0][0] + 2048 + w * 512;

  f32x4 acc[4][4] = {};
  for (int k0 = 0; k0 < K; k0 += 32) {
    __syncthreads();
    async_cp16(Ag0 + k0, la0);
    async_cp16(Ag1 + k0, la1);
    async_cp16(Bg0 + k0, lb0);
    async_cp16(Bg1 + k0, lb1);
    __syncthreads();
    bf16x8 af[4], bfr[4];
#pragma unroll
    for (int i = 0; i < 4; ++i)
      af[i] = *(const bf16x8*)&As[wm + i * 16 + l16][quad * 8];
#pragma unroll
    for (int j = 0; j < 4; ++j)
      bfr[j] = *(const bf16x8*)&Bs[wn + j * 16 + l16][quad * 8];
#pragma unroll
    for (int i = 0; i < 4; ++i)
#pragma unroll
      for (int j = 0; j < 4; ++j)
        acc[i][j] = __builtin_amdgcn_mfma_f32_16x16x32_bf16(af[i], bfr[j], acc[i][j], 0, 0, 0);
  }
#pragma unroll
  for (int i = 0; i < 4; ++i) {
    int row = m0 + wm + i * 16 + quad * 4;
#pragma unroll
    for (int j = 0; j < 4; ++j) {
      int col = n0 + wn + j * 16 + l16;
      float bv = bias ? bias[col] : 0.f;
#pragma unroll
      for (int r = 0; r < 4; ++r)
        st_out(&C[(size_t)(row + r) * ldc + col], acc[i][j][r] + bv);
    }
  }
}

// 64x128 variant
template <typename OutT>
static __device__ __forceinline__ void gemm_core_async64(const bf16_t* __restrict__ A, int lda,
                                                         const bf16_t* __restrict__ Bt, int ldb,
                                                         OutT* __restrict__ C, int ldc,
                                                         const float* __restrict__ bias, int K,
                                                         int bx, int by) {
  __shared__ bf16_t As[64][32];
  __shared__ bf16_t Bs[128][32];
  const int m0 = by * 64, n0 = bx * 128;
  const int t = threadIdx.x, w = t >> 6, lane = t & 63;
  const int wm = (w >> 1) * 32, wn = (w & 1) * 64;
  const int quad = lane >> 4, l16 = lane & 15;
  const int sra = lane >> 2, sca = (lane & 3) * 8;
  const bf16_t* Ag0 = A + (size_t)(m0 + w * 16 + sra) * lda + sca;
  const bf16_t* Bg0 = Bt + (size_t)(n0 + w * 16 + sra) * ldb + sca;
  const bf16_t* Bg1 = Bt + (size_t)(n0 + 64 + w * 16 + sra) * ldb + sca;
  bf16_t* la0 = &As[0][0] + w * 512;
  bf16_t* lb0 = &Bs[0][0] + w * 512;
  bf16_t* lb1 = &Bs[0][0] + 2048 + w * 512;

  f32x4 acc[2][4] = {};
  for (int k0 = 0; k0 < K; k0 += 32) {
    __syncthreads();
    async_cp16(Ag0 + k0, la0);
    async_cp16(Bg0 + k0, lb0);
    async_cp16(Bg1 + k0, lb1);
    __syncthreads();
    bf16x8 af[2], bfr[4];
#pragma unroll
    for (int i = 0; i < 2; ++i)
      af[i] = *(const bf16x8*)&As[wm + i * 16 + l16][quad * 8];
#pragma unroll
    for (int j = 0; j < 4; ++j)
      bfr[j] = *(const bf16x8*)&Bs[wn + j * 16 + l16][quad * 8];
#pragma unroll
    for (int i = 0; i < 2; ++i)
#pragma unroll
      for (int j = 0; j < 4; ++j)
        acc[i][j] = __builtin_amdgcn_mfma_f32_16x16x32_bf16(af[i], bfr[j], acc[i][j], 0, 0, 0);
  }
#pragma unroll
  for (int i = 0; i < 2; ++i) {
    int row = m0 + wm + i * 16 + quad * 4;
#pragma unroll
    for (int j = 0; j < 4; ++j) {
      int col = n0 + wn + j * 16 + l16;
      float bv = bias ? bias[col] : 0.f;
#pragma unroll
      for (int r = 0; r < 4; ++r)
        st_out(&C[(size_t)(row + r) * ldc + col], acc[i][j][r] + bv);
    }
  }
}

__global__ __launch_bounds__(256) void gemm_qkv(const bf16_t* __restrict__ A,
                                                const bf16_t* __restrict__ Bt,
                                                bf16_t* __restrict__ C,
                                                const float* __restrict__ biasN) {
  gemm_core_async<bf16_t>(A, 1024, Bt, 1024, C, 3328, biasN, 1024, blockIdx.x, blockIdx.y);
}

__global__ __launch_bounds__(256) void gemm_out(const bf16_t* __restrict__ A,
                                                const bf16_t* __restrict__ Bt,
                                                float* __restrict__ C,
                                                const float* __restrict__ bo) {
  gemm_core_async64<float>(A, 1024, Bt, 1024, C, 1024, bo, 1024, blockIdx.x, blockIdx.y);
}

__global__ __launch_bounds__(256) void gemm_wta(const bf16_t* __restrict__ qtaT,
                                                const bf16_t* __restrict__ ktaT,
                                                const bf16_t* __restrict__ Wqb,
                                                const bf16_t* __restrict__ Wkb,
                                                bf16_t* __restrict__ BtExt) {
  int z = blockIdx.z;
  gemm_core_async64<bf16_t>(z ? ktaT : qtaT, 1024, z ? Wkb : Wqb, 1024,
                            BtExt + (size_t)(3072 + z * 128) * 1024, 1024,
                            nullptr, 1024, blockIdx.x, blockIdx.y);
}

// =====================================================================
// fused torsion + q pre-scale by log2(e)/8
// =====================================================================
__global__ __launch_bounds__(256) void lin_torsion_fused(const bf16_t* __restrict__ qtbT,
                                                         const bf16_t* __restrict__ ktbT,
                                                         bf16_t* __restrict__ qkv,
                                                         const float* __restrict__ coupling) {
  __shared__ bf16_t As[128][136];
  __shared__ bf16_t Bs0[128][72];
  __shared__ bf16_t Bs1[128][72];
  const int z = blockIdx.z;
  const bf16_t* Low = qkv + 3072 + z * 128;
  const bf16_t* Tb = z ? ktbT : qtbT;
  bf16_t* X = qkv + z * 1024;

  const int m0 = blockIdx.y * 128, n0 = blockIdx.x * 128;
  const int t = threadIdx.x, w = t >> 6, lane = t & 63;
  const int wm = (w >> 1) * 64, wn = (w & 1) * 64;
  const int quad = lane >> 4, l16 = lane & 15;

  {
    const int sr = t >> 1, sc = (t & 1) * 64;
    const bf16_t* Ag = Low + (size_t)(m0 + sr) * 3328 + sc;
#pragma unroll
    for (int i = 0; i < 8; ++i)
      *(float4*)&As[sr][sc + 8 * i] = *(const float4*)(Ag + 8 * i);
    const int br = t >> 1, bc = (t & 1) * 32;
    const bf16_t* Bg0 = Tb + (size_t)(n0 + br) * 64 + bc;
    const bf16_t* Bg1 = Bg0 + 65536;
#pragma unroll
    for (int i = 0; i < 4; ++i) {
      *(float4*)&Bs0[br][bc + 8 * i] = *(const float4*)(Bg0 + 8 * i);
      *(float4*)&Bs1[br][bc + 8 * i] = *(const float4*)(Bg1 + 8 * i);
    }
  }
  __syncthreads();

  f32x4 acc0[4][4] = {}, acc1[4][4] = {};
#pragma unroll
  for (int ks = 0; ks < 2; ++ks) {
    bf16x8 a0[4], a1[4];
#pragma unroll
    for (int i = 0; i < 4; ++i) {
      a0[i] = *(const bf16x8*)&As[wm + i * 16 + l16][ks * 32 + quad * 8];
      a1[i] = *(const bf16x8*)&As[wm + i * 16 + l16][64 + ks * 32 + quad * 8];
    }
#pragma unroll
    for (int j = 0; j < 4; ++j) {
      bf16x8 b0 = *(const bf16x8*)&Bs0[wn + j * 16 + l16][ks * 32 + quad * 8];
      bf16x8 b1 = *(const bf16x8*)&Bs1[wn + j * 16 + l16][ks * 32 + quad * 8];
#pragma unroll
      for (int i = 0; i < 4; ++i) {
        acc0[i][j] = __builtin_amdgcn_mfma_f32_16x16x32_bf16(a0[i], b0, acc0[i][j], 0, 0, 0);
        acc1[i][j] = __builtin_amdgcn_mfma_f32_16x16x32_bf16(a1[i], b1, acc1[i][j], 0, 0, 0);
      }
    }
  }

  const float PI2 = 6.283185307179586f;
  const float sig = 1.f / (1.f + __expf(-coupling[0]));
  const float scale = z ? 1.f : 0.1803368801111204f;
#pragma unroll
  for (int i = 0; i < 4; ++i) {
#pragma unroll
    for (int j = 0; j < 4; ++j) {
#pragma unroll
      for (int r = 0; r < 4; ++r) {
        int row = m0 + wm + i * 16 + quad * 4 + r;
        int col = n0 + wn + j * 16 + l16;
        size_t idx = (size_t)row * 3328 + col;
        float l1 = acc0[i][j][r], l2 = acc1[i][j][r];
        float corr = __sinf(PI2 * l1) * l1 + __sinf(2.f * PI2 * l2) * l2 * 0.5f;
        X[idx] = (bf16_t)(((float)X[idx] + sig * corr) * scale);
      }
    }
  }
}

// =====================================================================
// Flash attention v7 = R4 structure (no key-split, (256,2): ~108 VGPR,
// no spill) + R5's verified conflict-free VT swizzle (8.8M -> 2.9M).
// Register-resident P via key permutation; Q/K fragments direct from
// global; only V round-trips LDS. Divide-by-l in epilogue, write aout.
// =====================================================================
__global__ __launch_bounds__(256, 2) void flash_attn(const bf16_t* __restrict__ qkv,
                                                     bf16_t* __restrict__ aout) {
  constexpr int LD = 3328, SEQ = 2048;
  const int qb = blockIdx.x, bh = blockIdx.y;
  const int b = bh >> 4, h = bh & 15;
  const size_t base = (size_t)b * SEQ * LD + h * 64;
  const bf16_t* Qg = qkv + base;
  const bf16_t* Kg = qkv + base + 1024;
  const bf16_t* Vg = qkv + base + 2048;

  __shared__ __align__(16) unsigned char smem[29696];
  bf16_t(*VT)[136] = (bf16_t(*)[136])smem;   // [64][136] loop-live
  float* LDSo = (float*)smem;                // [256][24] f32, epilogue
  float* Lred = (float*)(smem + 24576);      // [1024] f32, epilogue
  float* invL = (float*)(smem + 28672);      // [128] f32, epilogue

  const int t = threadIdx.x, w = t >> 6, lane = t & 63;
  const int kw = w >> 1, qw = w & 1;
  const int quad = lane >> 4, l16 = lane & 15;
  const int q0 = qb * 128;

  // ---- Q fragments direct from global ----
  bf16x8 qf[4][2];
  {
    const bf16_t* Qrow = Qg + (size_t)(q0 + qw * 64 + l16) * LD + quad * 8;
#pragma unroll
    for (int nf = 0; nf < 4; ++nf)
#pragma unroll
      for (int ks = 0; ks < 2; ++ks)
        qf[nf][ks] = *(const bf16x8*)(Qrow + (size_t)(nf * 16) * LD + ks * 32);
  }

  f32x4 o[4][4] = {};
  float l_part[4] = {0.f, 0.f, 0.f, 0.f};

  const int vg = t >> 3, vcb = (t & 7) * 8;
  // key-slot permutation (PV B-fragment order) ^ 3-bit row-XOR bank swizzle
  const int colb = (((vg >> 3) << 5) | ((vg & 3) << 3) | (((vg >> 2) & 1) << 2)) ^ ((t & 7) << 3);
  const bf16_t* Vbase = Vg + (size_t)(vg * 4) * LD + vcb;
  const bf16_t* Krow = Kg + (size_t)(kw * 64 + l16) * LD + quad * 8;

  for (int k0 = 0; k0 < SEQ; k0 += 128) {
    __syncthreads();  // prev-iter vf reads done
    {
      const bf16_t* vsrc = Vbase + (size_t)k0 * LD;
      union { float4 f; bf16_t h[8]; } vr[4];
#pragma unroll
      for (int kk = 0; kk < 4; ++kk)
        vr[kk].f = *(const float4*)(vsrc + (size_t)kk * LD);
#pragma unroll
      for (int cc = 0; cc < 8; ++cc) {
        union { bf16_t h[4]; uint2 u; } pk;
#pragma unroll
        for (int kk = 0; kk < 4; ++kk) pk.h[kk] = vr[kk].h[cc];
        *(uint2*)&VT[vcb + cc][colb] = pk.u;
      }
    }
    bf16x8 kf[4][2];
#pragma unroll
    for (int jk = 0; jk < 4; ++jk)
#pragma unroll
      for (int ks = 0; ks < 2; ++ks)
        kf[jk][ks] = *(const bf16x8*)(Krow + (size_t)(k0 + jk * 16) * LD + ks * 32);
    __syncthreads();  // VT ready

    f32x4 st[4][4] = {};
#pragma unroll
    for (int ks = 0; ks < 2; ++ks)
#pragma unroll
      for (int jk = 0; jk < 4; ++jk)
#pragma unroll
        for (int nf = 0; nf < 4; ++nf)
          st[jk][nf] = __builtin_amdgcn_mfma_f32_16x16x32_bf16(kf[jk][ks], qf[nf][ks], st[jk][nf], 0, 0, 0);

    bf16x8 Pp[2][4];
#pragma unroll
    for (int g = 0; g < 2; ++g)
#pragma unroll
      for (int nf = 0; nf < 4; ++nf) {
        union { bf16_t h[8]; bf16x8 v; } ph;
#pragma unroll
        for (int b2 = 0; b2 < 2; ++b2)
#pragma unroll
          for (int r = 0; r < 4; ++r) {
            float p = exp2f(st[g * 2 + b2][nf][r]);
            l_part[nf] += p;
            ph.h[b2 * 4 + r] = (bf16_t)p;
          }
        Pp[g][nf] = ph.v;
      }

#pragma unroll
    for (int g = 0; g < 2; ++g) {
      bf16x8 vf[4];
#pragma unroll
      for (int jd = 0; jd < 4; ++jd) {
        int row = jd * 16 + l16;
        int col = (kw * 64 + g * 32 + quad * 8) ^ ((((row >> 3) & 7)) << 3);
        vf[jd] = *(const bf16x8*)&VT[row][col];
      }
#pragma unroll
      for (int jd = 0; jd < 4; ++jd)
#pragma unroll
        for (int nf = 0; nf < 4; ++nf)
          o[jd][nf] = __builtin_amdgcn_mfma_f32_16x16x32_bf16(vf[jd], Pp[g][nf], o[jd][nf], 0, 0, 0);
    }
  }

  // ---- epilogue: reduce l and O across kw/quad, divide, store aout ----
  __syncthreads();
#pragma unroll
  for (int nf = 0; nf < 4; ++nf)
    Lred[((kw * 2 + qw) * 4 + quad) * 64 + nf * 16 + l16] = l_part[nf];
  __syncthreads();
  if (t < 128) {
    int qw2 = t >> 6, ql = t & 63;
    float s = 0.f;
#pragma unroll
    for (int kw2 = 0; kw2 < 2; ++kw2)
#pragma unroll
      for (int qd = 0; qd < 4; ++qd)
        s += Lred[((kw2 * 2 + qw2) * 4 + qd) * 64 + ql];
    invL[t] = 1.f / s;
  }
  __syncthreads();

  const int rq = t >> 1, rc0 = (t & 1) * 8;
#pragma unroll
  for (int jd = 0; jd < 4; ++jd) {
#pragma unroll
    for (int nf = 0; nf < 4; ++nf)
      *(f32x4*)&LDSo[(size_t)(kw * 128 + qw * 64 + nf * 16 + l16) * 24 + quad * 4] = o[jd][nf];
    __syncthreads();
    f32x4 a0 = *(const f32x4*)&LDSo[(size_t)rq * 24 + rc0];
    f32x4 a1 = *(const f32x4*)&LDSo[(size_t)(128 + rq) * 24 + rc0];
    f32x4 b0 = *(const f32x4*)&LDSo[(size_t)rq * 24 + rc0 + 4];
    f32x4 b1 = *(const f32x4*)&LDSo[(size_t)(128 + rq) * 24 + rc0 + 4];
    float iv = invL[rq];
    union { bf16_t h[8]; uint4 u; } pk;
#pragma unroll
    for (int r = 0; r < 4; ++r) {
      pk.h[r] = (bf16_t)((a0[r] + a1[r]) * iv);
      pk.h[4 + r] = (bf16_t)((b0[r] + b1[r]) * iv);
    }
    *(uint4*)&aout[(size_t)(b * SEQ + q0 + rq) * 1024 + h * 64 + jd * 16 + rc0] = pk.u;
    if (jd < 3) __syncthreads();
  }
}

// =====================================================================
// host launch
// =====================================================================
extern "C" void kernel_launch(void* const* d_in, const int* in_sizes, int n_in,
                              void* d_out, int out_size, void* d_ws, size_t ws_size,
                              hipStream_t stream) {
  const float* hs   = (const float*)d_in[0];
  const float* Wq   = (const float*)d_in[1];
  const float* bq   = (const float*)d_in[2];
  const float* Wk   = (const float*)d_in[3];
  const float* bk   = (const float*)d_in[4];
  const float* Wv   = (const float*)d_in[5];
  const float* bv   = (const float*)d_in[6];
  const float* Wo   = (const float*)d_in[7];
  const float* bo   = (const float*)d_in[8];
  const float* qta  = (const float*)d_in[9];
  const float* qtb  = (const float*)d_in[10];
  const float* kta  = (const float*)d_in[11];
  const float* ktb  = (const float*)d_in[12];
  const float* coup = (const float*)d_in[13];
  float* out = (float*)d_out;

  uint8_t* ws = (uint8_t*)d_ws;
  bf16_t* hsb   = (bf16_t*)(ws);              // dead after gemm_qkv -> aout
  bf16_t* aout  = (bf16_t*)(ws);              // flash output overlays hsb
  bf16_t* BtExt = (bf16_t*)(ws + 8388608);    // [3328][1024]
  bf16_t* WoT   = (bf16_t*)(ws + 16777216);   // 2 MB
  float*  biasN = (float*)(ws + 18874368);    // 16 KB
  bf16_t* qkv   = (bf16_t*)(ws + 18890752);   // [4096][3328] 27.3 MB
  bf16_t* Wqb   = (bf16_t*)(ws + 46153728);   // prep scratch
  bf16_t* Wkb   = (bf16_t*)(ws + 48250880);
  bf16_t* qtaT  = (bf16_t*)(ws + 50348032);
  bf16_t* ktaT  = (bf16_t*)(ws + 50610176);
  bf16_t* qtbT  = (bf16_t*)(ws + 50872320);
  bf16_t* ktbT  = (bf16_t*)(ws + 51134464);

  dim3 b256(256);

  prep<<<6669, b256, 0, stream>>>(hs, hsb, Wq, Wk, Wv, Wo, BtExt, WoT, Wqb, Wkb,
                                  qta, kta, qtaT, ktaT, qtb, ktb, qtbT, ktbT,
                                  bq, bk, bv, biasN);
  gemm_wta<<<dim3(8, 2, 2), b256, 0, stream>>>(qtaT, ktaT, Wqb, Wkb, BtExt);
  gemm_qkv<<<dim3(26, 32), b256, 0, stream>>>(hsb, BtExt, qkv, biasN);
  lin_torsion_fused<<<dim3(8, 32, 2), b256, 0, stream>>>(qtbT, ktbT, qkv, coup);
  flash_attn<<<dim3(16, 32), b256, 0, stream>>>(qkv, aout);
  gemm_out<<<dim3(8, 64), b256, 0, stream>>>(aout, WoT, out, bo);
}